// Round 8
// baseline (110.404 us; speedup 1.0000x reference)
//
#include <hip/hip_runtime.h>
#include <hip/hip_bf16.h>

// Problem constants (P=1 folded out everywhere)
#define NB   8      // batch
#define NA   8      // actions
#define ND   8      // dim_qk
#define NCH  64     // NA*ND q/k channels
#define GT   32     // grid T=H=W
#define KREG 216    // 6^3 halo voxels
#define IMS  40     // im2col/weight row stride in halfwords (80 B)

// LDS pool overlays (bytes): identical to r5 (verified layout/swizzles).
//  build window: xS[0,2304) pad-9 rows; BTS[2304,13824); imc[13824,31744)
//  attn  window: kAct[0,27648) xor-1 unit swizzle; vPl[27648,32384) stride 592;
//                qU[32384,40576) slot s=(a^row^x)&7; sc overlays kAct.
// Round-21: r7 structure (512-thread blocks, halved phase-C state) with the
// register cap RELAXED: (512,8) forced a 32/32 arch/acc split -> spill
// (VGPR=32, WRITE_SIZE 9.3MB, r7). (512,6) caps at ~85; natural allocation
// ~60 (r5 precedent). LDS admits 4 blocks (162304<=163840), so if natural
// VGPR <= 64 the HW still reaches 32 waves/CU; worst case 24 waves (1.5x r5).
#define KACT_OFF 0
#define VP_OFF   27648
#define VSTR     592
#define QU_OFF   32384
#define POOL_SZ  40576

typedef _Float16 h2_t  __attribute__((ext_vector_type(2)));
typedef _Float16 f16x4 __attribute__((ext_vector_type(4)));
typedef _Float16 f16x8 __attribute__((ext_vector_type(8)));
typedef float    f32x4 __attribute__((ext_vector_type(4)));

static __device__ __forceinline__ unsigned pack_h2(float a, float b) {
#if __has_builtin(__builtin_amdgcn_cvt_pkrtz)
    return __builtin_bit_cast(unsigned, __builtin_amdgcn_cvt_pkrtz(a, b));
#else
    unsigned short ha = __builtin_bit_cast(unsigned short, (_Float16)a);
    unsigned short hb = __builtin_bit_cast(unsigned short, (_Float16)b);
    return (unsigned)ha | ((unsigned)hb << 16);
#endif
}

static __device__ __forceinline__ float dot2(unsigned k, unsigned q, float c) {
#if __has_builtin(__builtin_amdgcn_fdot2)
    return __builtin_amdgcn_fdot2(__builtin_bit_cast(h2_t, k),
                                  __builtin_bit_cast(h2_t, q), c, false);
#else
    h2_t a = __builtin_bit_cast(h2_t, k), b = __builtin_bit_cast(h2_t, q);
    return c + (float)a[0] * (float)b[0] + (float)a[1] * (float)b[1];
#endif
}

// THREE-TIMES-CONFIRMED RULE (r9/r13): one action's state per thread.
// r6 RULE: k/v neighborhood reads MUST be LDS-staged (global path 2x slower).
// r7 RULE: never launch_bounds-cap below ~56 VGPR here -- the MFMA arch/acc
// split halves the arch budget and spills af[] (WRITE_SIZE 2->9.3MB).
__launch_bounds__(512, 6)
__global__ void avi_kernel(const float* __restrict__ values,
                           const float* __restrict__ rewards,
                           const float* __restrict__ w_qk,
                           const float* __restrict__ w_v,
                           float* __restrict__ out) {
    __shared__ __align__(16) char pool[POOL_SZ];
    float*    xS   = (float*)(pool + 0);        // [8][72]: z*72 + y*9 + x
    _Float16* BTSl = (_Float16*)(pool + 2304);
    _Float16* imc  = (_Float16*)(pool + 13824);
    char*     qU   = pool + QU_OFF;

    const int tid  = threadIdx.x;
    const int bb   = blockIdx.x >> 9;      // batch
    const int tile = blockIdx.x & 511;     // 8x8x8 tiles of 4^3
    const int tz = tile >> 6, ty = (tile >> 3) & 7, tx = tile & 7;
    const int g0z = tz * 4, g0y = ty * 4, g0x = tx * 4;
    const int base_in = bb * (GT * GT * GT);

    // ---- Phase A: x staging (512 threads = 512 halo cells, one shot) ----
    {
        int lz = tid >> 6, ly = (tid >> 3) & 7, lx = tid & 7;
        int gz = g0z + lz - 2, gy = g0y + ly - 2, gx = g0x + lx - 2;
        float v = 0.f;
        if ((unsigned)gz < 32u && (unsigned)gy < 32u && (unsigned)gx < 32u) {
            int idx = base_in + gz * 1024 + gy * 32 + gx;
            v = values[idx] + rewards[idx];
        }
        xS[lz * 72 + ly * 9 + lx] = v;
    }
    if (tid < 144) {
        float r[28];
        r[27] = 0.f;
        if (tid < 64) {
            const float* w = w_qk + (NCH + tid) * 27;
            #pragma unroll
            for (int j = 0; j < 27; ++j) r[j] = w[j];
        } else if (tid < 72) {
            int a = tid - 64;
            float m = -1e30f;
            #pragma unroll
            for (int j = 0; j < 27; ++j) { r[j] = w_v[a * 27 + j]; m = fmaxf(m, r[j]); }
            float s = 0.f;
            #pragma unroll
            for (int j = 0; j < 27; ++j) { r[j] = __expf(r[j] - m); s += r[j]; }
            float inv = 1.f / s;
            #pragma unroll
            for (int j = 0; j < 27; ++j) r[j] *= inv;
        } else if (tid < 80) {
            #pragma unroll
            for (int j = 0; j < 27; ++j) r[j] = 0.f;
        } else {
            const float* w = w_qk + (tid - 80) * 27;
            const float L2E = 1.44269504f;
            #pragma unroll
            for (int j = 0; j < 27; ++j) r[j] = w[j] * L2E;
        }
        unsigned* dst = (unsigned*)(BTSl + tid * IMS);
        #pragma unroll
        for (int p = 0; p < 14; ++p) dst[p] = pack_h2(r[2 * p], r[2 * p + 1]);
        #pragma unroll
        for (int p = 14; p < 20; ++p) dst[p] = 0u;
    }
    __syncthreads();

    // ---- Phase B1: im2col fp16 [224][IMS] (waves 0-3) ----
    if (tid < 224) {
        unsigned rowU[16];
        if (tid < KREG) {
            int vz = tid / 36, rem = tid - vz * 36, vy = rem / 6, vx = rem - vy * 6;
            int gz = g0z + vz - 1, gy = g0y + vy - 1, gx = g0x + vx - 1;
            float mask = ((unsigned)gz < 32u && (unsigned)gy < 32u && (unsigned)gx < 32u)
                             ? 1.f : 0.f;
            float xr[27];
            #pragma unroll
            for (int t = 0; t < 27; ++t) {
                int dz = t / 9, dy = (t / 3) % 3, dx = t % 3;
                xr[t] = xS[(vz + dz) * 72 + (vy + dy) * 9 + (vx + dx)] * mask;
            }
            #pragma unroll
            for (int p = 0; p < 13; ++p) rowU[p] = pack_h2(xr[2 * p], xr[2 * p + 1]);
            rowU[13] = pack_h2(xr[26], 0.f);
            rowU[14] = rowU[15] = 0u;
        } else {
            #pragma unroll
            for (int p = 0; p < 16; ++p) rowU[p] = 0u;
        }
        int4* dst = (int4*)((char*)imc + tid * (IMS * 2));
        dst[0] = make_int4(rowU[0], rowU[1], rowU[2], rowU[3]);
        dst[1] = make_int4(rowU[4], rowU[5], rowU[6], rowU[7]);
        dst[2] = make_int4(rowU[8], rowU[9], rowU[10], rowU[11]);
        dst[3] = make_int4(rowU[12], rowU[13], rowU[14], rowU[15]);
    }

    const int lane = tid & 63;
    const int wave = tid >> 6;            // 0..7
    const int quad = lane >> 4;
    const int l15  = lane & 15;

    // A-frags: all 8 waves load the same 9 frags (floor-rate, audited)
    f16x8 af[9];
    #pragma unroll
    for (int mt = 0; mt < 9; ++mt)
        af[mt] = *(const f16x8*)(BTSl + (mt * 16 + l15) * IMS + quad * 8);

    __syncthreads();   // im2col ready

    f16x8 bf[2];
    #pragma unroll
    for (int i = 0; i < 2; ++i) {
        int nt = wave + i * 8;
        if (nt < 14)
            bf[i] = *(const f16x8*)(imc + (nt * 16 + l15) * IMS + quad * 8);
    }

    __syncthreads();   // frag loads done -> build window reusable as planes

    // ---- Phase B2: unified MFMA (2 nt-iters/wave); k,v,q -> swizzled LDS ----
    for (int i = 0; i < 2; ++i) {
        int nt = wave + i * 8;
        if (nt >= 14) break;
        int n = nt * 16 + l15;
        bool nvalid = (n < KREG);
        int vz = n / 36, rm = n - vz * 36, vy = rm / 6, vx = rm - vy * 6;
        bool ctr = ((unsigned)(vz - 1) < 4u) && ((unsigned)(vy - 1) < 4u) &&
                   ((unsigned)(vx - 1) < 4u);
        int cvox = (vz - 1) * 16 + (vy - 1) * 4 + (vx - 1);
        int kp_byte = (n * 16) ^ ((vz & 1) << 4);
        int qoff = cvox * 128 +
                   ((((quad >> 1) ^ (cvox >> 2) ^ (cvox & 3)) & 7) << 4) +
                   (quad & 1) * 8;
        #pragma unroll
        for (int mt = 0; mt < 9; ++mt) {
            f32x4 d = __builtin_amdgcn_mfma_f32_16x16x32_f16(
                af[mt], bf[i], (f32x4){0.f, 0.f, 0.f, 0.f}, 0, 0, 0);
            if (mt < 4) {                       // k ch = mt*16 + quad*4 + reg
                if (nvalid) {
                    int a = mt * 2 + (quad >> 1);
                    int2 w2;
                    w2.x = (int)pack_h2(d[0], d[1]);
                    w2.y = (int)pack_h2(d[2], d[3]);
                    *(int2*)(pool + KACT_OFF + a * 3456 + kp_byte + (quad & 1) * 8) = w2;
                }
            } else if (mt == 4) {               // v actions quad*4+reg (quad<2)
                if (nvalid && quad < 2) {
                    #pragma unroll
                    for (int j = 0; j < 4; ++j)
                        *(_Float16*)(pool + VP_OFF + (quad * 4 + j) * VSTR +
                                     vz * 96 + vy * 16 + vx * 2) = (_Float16)d[j];
                }
            } else {                            // q ch = (mt-5)*16 + quad*4
                if (ctr) {
                    int2 w2;
                    w2.x = (int)pack_h2(d[0], d[1]);
                    w2.y = (int)pack_h2(d[2], d[3]);
                    *(int2*)(qU + (qoff ^ ((mt - 5) << 5))) = w2;
                }
            }
        }
    }
    __syncthreads();

    // ---- Phase C: 2-voxel x-half per thread, 1 action, 4.5-step halves ----
    // tid = h*256 + a*32 + xh*16 + row : row in bits0-3 keeps all LDS read
    // groups at the audited r5 floor rates.
    const int row  = tid & 15;
    const int xh   = (tid >> 4) & 1;
    const int a    = (tid >> 5) & 7;
    const int h    = tid >> 8;            // wave-pair half (wave-uniform)
    const int clz2 = row >> 2, cly2 = row & 3;
    const int X0   = xh * 2;

    // q: 2 immediate-offset b128 loads (slot = (a^row^x)&7, floor-rate)
    unsigned qp[2][4];
    {
        const char* qb = qU + row * 512;
        const int   u0 = (a ^ row) & 7;
        #pragma unroll
        for (int xl = 0; xl < 2; ++xl) {
            int x = X0 + xl;
            const int4 qv = *(const int4*)(qb + x * 128 + ((u0 ^ x) << 4));
            qp[xl][0] = (unsigned)qv.x; qp[xl][1] = (unsigned)qv.y;
            qp[xl][2] = (unsigned)qv.z; qp[xl][3] = (unsigned)qv.w;
        }
    }

    float ssum[2] = {0.f, 0.f};
    float acc[2]  = {0.f, 0.f};

    // xor-parity pointers with X0 folded in: all phase-C reads are
    // immediate-offset ds_reads off PAx/PBx/vb.
    const int   p   = clz2 & 1;
    const char* b0  = pool + KACT_OFF + a * 3456 + clz2 * 576 + cly2 * 96;
    const char* PAx = b0 + p * 16 + X0 * 16;
    const char* PBx = b0 + 16 - p * 16 + X0 * 16;
    const char* vb  = pool + VP_OFF + a * VSTR + clz2 * 96 + cly2 * 16 + X0 * 2;

    // Full step: 4 rows (X0..X0+3), 2 voxels x 3 dx = 6 dots.
#define STEP2(PTA, PTB, KI, VI) do {                                          \
        int4 km[4];                                                           \
        km[0] = *(const int4*)((PTA) + (KI));                                 \
        km[1] = *(const int4*)((PTB) + (KI));                                 \
        km[2] = *(const int4*)((PTA) + (KI) + 32);                            \
        km[3] = *(const int4*)((PTB) + (KI) + 32);                            \
        f16x4 vv = *(const f16x4*)(vb + (VI));                                \
        float vf[4];                                                          \
        _Pragma("unroll")                                                     \
        for (int j = 0; j < 4; ++j) vf[j] = (float)vv[j];                     \
        _Pragma("unroll")                                                     \
        for (int xl = 0; xl < 2; ++xl) {                                      \
            _Pragma("unroll")                                                 \
            for (int dx = 0; dx < 3; ++dx) {                                  \
                const int j = xl + dx;                                        \
                float s = dot2((unsigned)km[j].x, qp[xl][0],                  \
                          dot2((unsigned)km[j].y, qp[xl][1],                  \
                          dot2((unsigned)km[j].z, qp[xl][2],                  \
                          dot2((unsigned)km[j].w, qp[xl][3], 0.f))));         \
                float e = exp2f(s);                                           \
                ssum[xl] += e;                                                \
                acc[xl] = fmaf(e, vf[j], acc[xl]);                            \
            }                                                                 \
        }                                                                     \
    } while (0)

    // Quarter step: one voxel (XL), 3 rows, 3 dots (balances the 9th step).
#define QSTEP(PTA, PTB, KI, VI, XL) do {                                      \
        int4 km[3];                                                           \
        if ((XL) == 0) {                                                      \
            km[0] = *(const int4*)((PTA) + (KI));                             \
            km[1] = *(const int4*)((PTB) + (KI));                             \
            km[2] = *(const int4*)((PTA) + (KI) + 32);                        \
        } else {                                                              \
            km[0] = *(const int4*)((PTB) + (KI));                             \
            km[1] = *(const int4*)((PTA) + (KI) + 32);                        \
            km[2] = *(const int4*)((PTB) + (KI) + 32);                        \
        }                                                                     \
        f16x4 vv = *(const f16x4*)(vb + (VI));                                \
        _Pragma("unroll")                                                     \
        for (int dx = 0; dx < 3; ++dx) {                                      \
            float s = dot2((unsigned)km[dx].x, qp[XL][0],                     \
                      dot2((unsigned)km[dx].y, qp[XL][1],                     \
                      dot2((unsigned)km[dx].z, qp[XL][2],                     \
                      dot2((unsigned)km[dx].w, qp[XL][3], 0.f))));            \
            float e = exp2f(s);                                               \
            ssum[XL] += e;                                                    \
            acc[XL] = fmaf(e, (float)vv[(XL) + dx], acc[XL]);                 \
        }                                                                     \
    } while (0)

    if (h == 0) {
        STEP2(PAx, PBx, 0,    0);
        STEP2(PAx, PBx, 96,   16);
        STEP2(PAx, PBx, 192,  32);
        STEP2(PBx, PAx, 576,  96);
        QSTEP(PBx, PAx, 672, 112, 0);
    } else {
        QSTEP(PBx, PAx, 672, 112, 1);
        STEP2(PBx, PAx, 768,  128);
        STEP2(PAx, PBx, 1152, 192);
        STEP2(PAx, PBx, 1248, 208);
        STEP2(PAx, PBx, 1344, 224);
    }
#undef STEP2
#undef QSTEP

    // scratch overlays dead kAct region; barrier before the overlay write
    float2* sc = (float2*)pool;
    __syncthreads();
    #pragma unroll
    for (int xl = 0; xl < 2; ++xl) {
        int vox = row * 4 + X0 + xl;
        sc[vox * 17 + a * 2 + h] = make_float2(ssum[xl], acc[xl]);
    }
    __syncthreads();

    // ---- merge halves, softmax-normalize, max over actions -> output ----
    if (tid < 64) {
        float best = -1e30f;
        #pragma unroll
        for (int aa = 0; aa < 8; ++aa) {
            float2 p0 = sc[tid * 17 + aa * 2 + 0];
            float2 p1 = sc[tid * 17 + aa * 2 + 1];
            best = fmaxf(best, (p0.y + p1.y) / (p0.x + p1.x));
        }
        int lz2 = tid >> 4, ly2 = (tid >> 2) & 3, lx2 = tid & 3;
        int o = base_in + (g0z + lz2) * 1024 + (g0y + ly2) * 32 + (g0x + lx2);
        out[o] = best;
    }
}

extern "C" void kernel_launch(void* const* d_in, const int* in_sizes, int n_in,
                              void* d_out, int out_size, void* d_ws, size_t ws_size,
                              hipStream_t stream) {
    const float* values  = (const float*)d_in[0];
    const float* rewards = (const float*)d_in[1];
    const float* w_qk    = (const float*)d_in[2];
    const float* w_v     = (const float*)d_in[3];
    avi_kernel<<<NB * 512, 512, 0, stream>>>(values, rewards, w_qk, w_v,
                                             (float*)d_out);
}

// Round 10
// 102.814 us; speedup vs baseline: 1.0738x; 1.0738x over previous
//
#include <hip/hip_runtime.h>
#include <hip/hip_bf16.h>

// Problem constants (P=1 folded out everywhere)
#define NB   8      // batch
#define NA   8      // actions
#define ND   8      // dim_qk
#define NCH  64     // NA*ND q/k channels
#define GT   32     // grid T=H=W
#define KREG 216    // 6^3 halo voxels
#define IMS  40     // im2col/weight row stride in halfwords (80 B)

// LDS pool overlays (bytes):
//  build window: xS[0,2304) pad-9 rows; BTS[2304,13824); imc[13824,31744)
//  attn  window (r5-verified, 102.5us harness / 52.4us dispatch):
//    kAct[0,27648)   : 8 action-planes [216 units x 16B], unit p = n ^ (z&1)
//    vPl [27648,32384): 8 action-planes, stride 592B
//    qU  [32384,40576): 64 vox x 8 slots x 16B, slot s=(a^vox>>2^vox&3)&7
//    sc overlays kAct after last STEP (barrier-protected): [vox][17] float2
#define KACT_OFF 0
#define VP_OFF   27648
#define VSTR     592
#define QU_OFF   32384
#define POOL_SZ  40576    // <= 40960 -> 4 blocks/CU

// FINAL MODEL (r2-r8 evidence): kernel is jointly LDS-pipe (~60-75% of the
// measured-achievable 85B/cy ds_read rate) + VALU (~60%) bound, coupled by
// dot->exp->fma chains. SQ_LDS_BANK_CONFLICT ~7M is mostly the mandatory
// b128 8-slot serialization being counted (audit: reads at exact floor).
// Falsified levers: conflicts (r2-r5 flat), occupancy x2 (r7/r8 worse),
// issue count (r4 flat), global-memory split (r6 2x worse), 512-thd (r8).

typedef _Float16 h2_t  __attribute__((ext_vector_type(2)));
typedef _Float16 f16x4 __attribute__((ext_vector_type(4)));
typedef _Float16 f16x8 __attribute__((ext_vector_type(8)));
typedef float    f32x4 __attribute__((ext_vector_type(4)));

static __device__ __forceinline__ unsigned pack_h2(float a, float b) {
#if __has_builtin(__builtin_amdgcn_cvt_pkrtz)
    return __builtin_bit_cast(unsigned, __builtin_amdgcn_cvt_pkrtz(a, b));
#else
    unsigned short ha = __builtin_bit_cast(unsigned short, (_Float16)a);
    unsigned short hb = __builtin_bit_cast(unsigned short, (_Float16)b);
    return (unsigned)ha | ((unsigned)hb << 16);
#endif
}

static __device__ __forceinline__ float dot2(unsigned k, unsigned q, float c) {
#if __has_builtin(__builtin_amdgcn_fdot2)
    return __builtin_amdgcn_fdot2(__builtin_bit_cast(h2_t, k),
                                  __builtin_bit_cast(h2_t, q), c, false);
#else
    h2_t a = __builtin_bit_cast(h2_t, k), b = __builtin_bit_cast(h2_t, q);
    return c + (float)a[0] * (float)b[0] + (float)a[1] * (float)b[1];
#endif
}

// THREE-TIMES-CONFIRMED RULE (r9/r13): one action's state per thread.
// r6 RULE: k/v neighborhood reads MUST be LDS-staged (global path 2x slower).
// r7 RULE: never launch_bounds-cap below ~56 VGPR (arch/acc split spills af).
// r8 RULE: 256-thd blocks > 512-thd here (x-run reuse + af non-redundancy).
__launch_bounds__(256, 4)
__global__ void avi_kernel(const float* __restrict__ values,
                           const float* __restrict__ rewards,
                           const float* __restrict__ w_qk,
                           const float* __restrict__ w_v,
                           float* __restrict__ out) {
    __shared__ __align__(16) char pool[POOL_SZ];
    float*    xS   = (float*)(pool + 0);        // [8][72]: z*72 + y*9 + x
    _Float16* BTSl = (_Float16*)(pool + 2304);
    _Float16* imc  = (_Float16*)(pool + 13824);
    char*     qU   = pool + QU_OFF;

    const int tid  = threadIdx.x;
    const int bb   = blockIdx.x >> 9;      // batch
    const int tile = blockIdx.x & 511;     // 8x8x8 tiles of 4^3
    const int tz = tile >> 6, ty = (tile >> 3) & 7, tx = tile & 7;
    const int g0z = tz * 4, g0y = ty * 4, g0x = tx * 4;
    const int base_in = bb * (GT * GT * GT);

    // ---- Phase A: x staging + in-block weight-image build ----
    for (int i = tid; i < 512; i += 256) {
        int lz = i >> 6, ly = (i >> 3) & 7, lx = i & 7;
        int gz = g0z + lz - 2, gy = g0y + ly - 2, gx = g0x + lx - 2;
        float v = 0.f;
        if ((unsigned)gz < 32u && (unsigned)gy < 32u && (unsigned)gx < 32u) {
            int idx = base_in + gz * 1024 + gy * 32 + gx;
            v = values[idx] + rewards[idx];
        }
        xS[lz * 72 + ly * 9 + lx] = v;
    }
    if (tid < 144) {
        float r[28];
        r[27] = 0.f;
        if (tid < 64) {
            const float* w = w_qk + (NCH + tid) * 27;
            #pragma unroll
            for (int j = 0; j < 27; ++j) r[j] = w[j];
        } else if (tid < 72) {
            int a = tid - 64;
            float m = -1e30f;
            #pragma unroll
            for (int j = 0; j < 27; ++j) { r[j] = w_v[a * 27 + j]; m = fmaxf(m, r[j]); }
            float s = 0.f;
            #pragma unroll
            for (int j = 0; j < 27; ++j) { r[j] = __expf(r[j] - m); s += r[j]; }
            float inv = 1.f / s;
            #pragma unroll
            for (int j = 0; j < 27; ++j) r[j] *= inv;
        } else if (tid < 80) {
            #pragma unroll
            for (int j = 0; j < 27; ++j) r[j] = 0.f;
        } else {
            const float* w = w_qk + (tid - 80) * 27;
            const float L2E = 1.44269504f;
            #pragma unroll
            for (int j = 0; j < 27; ++j) r[j] = w[j] * L2E;
        }
        unsigned* dst = (unsigned*)(BTSl + tid * IMS);
        #pragma unroll
        for (int p = 0; p < 14; ++p) dst[p] = pack_h2(r[2 * p], r[2 * p + 1]);
        #pragma unroll
        for (int p = 14; p < 20; ++p) dst[p] = 0u;
    }
    __syncthreads();

    // ---- Phase B1: im2col fp16 [224][IMS] (OOB voxel columns zeroed) ----
    if (tid < 224) {
        unsigned rowU[16];
        if (tid < KREG) {
            int vz = tid / 36, rem = tid - vz * 36, vy = rem / 6, vx = rem - vy * 6;
            int gz = g0z + vz - 1, gy = g0y + vy - 1, gx = g0x + vx - 1;
            float mask = ((unsigned)gz < 32u && (unsigned)gy < 32u && (unsigned)gx < 32u)
                             ? 1.f : 0.f;
            float xr[27];
            #pragma unroll
            for (int t = 0; t < 27; ++t) {
                int dz = t / 9, dy = (t / 3) % 3, dx = t % 3;
                xr[t] = xS[(vz + dz) * 72 + (vy + dy) * 9 + (vx + dx)] * mask;
            }
            #pragma unroll
            for (int p = 0; p < 13; ++p) rowU[p] = pack_h2(xr[2 * p], xr[2 * p + 1]);
            rowU[13] = pack_h2(xr[26], 0.f);
            rowU[14] = rowU[15] = 0u;
        } else {
            #pragma unroll
            for (int p = 0; p < 16; ++p) rowU[p] = 0u;
        }
        int4* dst = (int4*)((char*)imc + tid * (IMS * 2));
        dst[0] = make_int4(rowU[0], rowU[1], rowU[2], rowU[3]);
        dst[1] = make_int4(rowU[4], rowU[5], rowU[6], rowU[7]);
        dst[2] = make_int4(rowU[8], rowU[9], rowU[10], rowU[11]);
        dst[3] = make_int4(rowU[12], rowU[13], rowU[14], rowU[15]);
    }

    const int lane = tid & 63;
    const int wave = tid >> 6;
    const int quad = lane >> 4;
    const int l15  = lane & 15;

    // A-frags: A[m=l15][k=quad*8+j]; stride 40 halfs -> floor (audited)
    f16x8 af[9];
    #pragma unroll
    for (int mt = 0; mt < 9; ++mt)
        af[mt] = *(const f16x8*)(BTSl + (mt * 16 + l15) * IMS + quad * 8);

    __syncthreads();   // im2col ready

    f16x8 bf[4];
    #pragma unroll
    for (int i = 0; i < 4; ++i) {
        int nt = wave + i * 4;
        if (nt < 14)
            bf[i] = *(const f16x8*)(imc + (nt * 16 + l15) * IMS + quad * 8);
    }

    __syncthreads();   // frag loads done -> build window reusable as planes

    // ---- Phase B2: unified MFMA; k,v,q -> swizzled LDS ----
    for (int i = 0; i < 4; ++i) {
        int nt = wave + i * 4;
        if (nt >= 14) break;
        int n = nt * 16 + l15;
        bool nvalid = (n < KREG);
        int vz = n / 36, rm = n - vz * 36, vy = rm / 6, vx = rm - vy * 6;
        bool ctr = ((unsigned)(vz - 1) < 4u) && ((unsigned)(vy - 1) < 4u) &&
                   ((unsigned)(vx - 1) < 4u);
        int cvox = (vz - 1) * 16 + (vy - 1) * 4 + (vx - 1);
        // physical k unit byte offset: (n ^ (z&1)) * 16
        int kp_byte = (n * 16) ^ ((vz & 1) << 4);
        // q store base: slot s = (a ^ cvox>>2 ^ cvox&3)&7 with a=(mt-5)*2+qh
        int qoff = cvox * 128 +
                   ((((quad >> 1) ^ (cvox >> 2) ^ (cvox & 3)) & 7) << 4) +
                   (quad & 1) * 8;
        #pragma unroll
        for (int mt = 0; mt < 9; ++mt) {
            f32x4 d = __builtin_amdgcn_mfma_f32_16x16x32_f16(
                af[mt], bf[i], (f32x4){0.f, 0.f, 0.f, 0.f}, 0, 0, 0);
            if (mt < 4) {                       // k ch = mt*16 + quad*4 + reg
                if (nvalid) {
                    int a = mt * 2 + (quad >> 1);       // action plane
                    int2 w2;
                    w2.x = (int)pack_h2(d[0], d[1]);
                    w2.y = (int)pack_h2(d[2], d[3]);
                    *(int2*)(pool + KACT_OFF + a * 3456 + kp_byte + (quad & 1) * 8) = w2;
                }
            } else if (mt == 4) {               // v actions quad*4+reg (quad<2)
                if (nvalid && quad < 2) {
                    #pragma unroll
                    for (int j = 0; j < 4; ++j)
                        *(_Float16*)(pool + VP_OFF + (quad * 4 + j) * VSTR +
                                     vz * 96 + vy * 16 + vx * 2) = (_Float16)d[j];
                }
            } else {                            // q ch = (mt-5)*16 + quad*4
                if (ctr) {
                    int2 w2;
                    w2.x = (int)pack_h2(d[0], d[1]);
                    w2.y = (int)pack_h2(d[2], d[3]);
                    *(int2*)(qU + (qoff ^ ((mt - 5) << 5))) = w2;
                }
            }
        }
    }
    __syncthreads();

    // ---- Phase C: 4-voxel x-run per thread, 1 action, balanced step split.
    //      All k/v reads are immediate-offset ds_reads off 3 base pointers. ----
    const int a    = (tid >> 4) & 7;      // action (wave holds 4 actions)
    const int row  = tid & 15;            // clz2*4 + cly2
    const int h    = tid >> 7;            // wave-pair half (wave-uniform!)
    const int clz2 = row >> 2, cly2 = row & 3;

    // q: 4 b128 loads, slot = u0^x (floor-rate: u0=(a^row)&7 varies per lane)
    unsigned qp[4][4];
    {
        const char* qb = qU + row * 512;
        const int   u0 = (a ^ row) & 7;
        #pragma unroll
        for (int x = 0; x < 4; ++x) {
            const int4 qv = *(const int4*)(qb + x * 128 + ((u0 ^ x) << 4));
            qp[x][0] = (unsigned)qv.x; qp[x][1] = (unsigned)qv.y;
            qp[x][2] = (unsigned)qv.z; qp[x][3] = (unsigned)qv.w;
        }
    }

    float ssum[4] = {0.f, 0.f, 0.f, 0.f};
    float acc[4]  = {0.f, 0.f, 0.f, 0.f};

    // xor-parity base pointers: every STEP k-load = PA/PB + compile-time imm
    const int   p   = clz2 & 1;
    const char* b0  = pool + KACT_OFF + a * 3456 + clz2 * 576 + cly2 * 96;
    const char* PAp = b0 + p * 16;
    const char* PBp = b0 + 16 - p * 16;
    const char* vb  = pool + VP_OFF + a * VSTR + clz2 * 96 + cly2 * 16;

    // Full (dz,dy) step: 6 halo rows once, 12 dots. KI = DZ*576+DY*96,
    // VI = DZ*96+DY*16. PTA/PTB swap roles when DZ is odd.
    // v-read narrowed b128 -> b64+b32 (only 6 of 8 halfs used; r8 trim).
#define STEP(PTA, PTB, KI, VI) do {                                           \
        int4 km[6];                                                           \
        km[0] = *(const int4*)((PTA) + (KI));                                 \
        km[1] = *(const int4*)((PTB) + (KI));                                 \
        km[2] = *(const int4*)((PTA) + (KI) + 32);                            \
        km[3] = *(const int4*)((PTB) + (KI) + 32);                            \
        km[4] = *(const int4*)((PTA) + (KI) + 64);                            \
        km[5] = *(const int4*)((PTB) + (KI) + 64);                            \
        f16x4 vv4 = *(const f16x4*)(vb + (VI));                               \
        h2_t  vv2 = *(const h2_t*)(vb + (VI) + 8);                            \
        float vf[6];                                                          \
        vf[0] = (float)vv4[0]; vf[1] = (float)vv4[1];                         \
        vf[2] = (float)vv4[2]; vf[3] = (float)vv4[3];                         \
        vf[4] = (float)vv2[0]; vf[5] = (float)vv2[1];                         \
        _Pragma("unroll")                                                     \
        for (int x = 0; x < 4; ++x) {                                         \
            _Pragma("unroll")                                                 \
            for (int dx = 0; dx < 3; ++dx) {                                  \
                const int j = x + dx;                                         \
                float s = dot2((unsigned)km[j].x, qp[x][0],                   \
                          dot2((unsigned)km[j].y, qp[x][1],                   \
                          dot2((unsigned)km[j].z, qp[x][2],                   \
                          dot2((unsigned)km[j].w, qp[x][3], 0.f))));          \
                float e = exp2f(s);                                           \
                ssum[x] += e;                                                 \
                acc[x] = fmaf(e, vf[j], acc[x]);                              \
            }                                                                 \
        }                                                                     \
    } while (0)

    // Half step: x in {X0,X0+1} (X0 even), 4 rows, 6 dots.
#define HSTEP(PTA, PTB, KI, VI, X0) do {                                      \
        int4 km[4];                                                           \
        km[0] = *(const int4*)((PTA) + (KI) + (X0) * 16);                     \
        km[1] = *(const int4*)((PTB) + (KI) + (X0) * 16);                     \
        km[2] = *(const int4*)((PTA) + (KI) + (X0) * 16 + 32);                \
        km[3] = *(const int4*)((PTB) + (KI) + (X0) * 16 + 32);                \
        h2_t vva = *(const h2_t*)(vb + (VI) + (X0) * 2);                      \
        h2_t vvb = *(const h2_t*)(vb + (VI) + (X0) * 2 + 4);                  \
        float vf[4];                                                          \
        vf[0] = (float)vva[0]; vf[1] = (float)vva[1];                         \
        vf[2] = (float)vvb[0]; vf[3] = (float)vvb[1];                         \
        _Pragma("unroll")                                                     \
        for (int x = (X0); x < (X0) + 2; ++x) {                               \
            _Pragma("unroll")                                                 \
            for (int dx = 0; dx < 3; ++dx) {                                  \
                const int j = x + dx - (X0);                                  \
                float s = dot2((unsigned)km[j].x, qp[x][0],                   \
                          dot2((unsigned)km[j].y, qp[x][1],                   \
                          dot2((unsigned)km[j].z, qp[x][2],                   \
                          dot2((unsigned)km[j].w, qp[x][3], 0.f))));          \
                float e = exp2f(s);                                           \
                ssum[x] += e;                                                 \
                acc[x] = fmaf(e, vf[j], acc[x]);                              \
            }                                                                 \
        }                                                                     \
    } while (0)

    if (h == 0) {
        STEP(PAp, PBp, 0,    0);
        STEP(PAp, PBp, 96,   16);
        STEP(PAp, PBp, 192,  32);
        STEP(PBp, PAp, 576,  96);
        HSTEP(PBp, PAp, 672, 112, 0);
    } else {
        HSTEP(PBp, PAp, 672, 112, 2);
        STEP(PBp, PAp, 768,  128);
        STEP(PAp, PBp, 1152, 192);
        STEP(PAp, PBp, 1248, 208);
        STEP(PAp, PBp, 1344, 224);
    }
#undef STEP
#undef HSTEP

    // scratch overlays dead kAct region; barrier before the overlay write
    float2* sc = (float2*)pool;
    __syncthreads();
    #pragma unroll
    for (int x = 0; x < 4; ++x)
        sc[(row * 4 + x) * 17 + a * 2 + h] = make_float2(ssum[x], acc[x]);
    __syncthreads();

    // ---- merge halves, softmax-normalize, max over actions -> output ----
    if (tid < 64) {
        float best = -1e30f;
        #pragma unroll
        for (int aa = 0; aa < 8; ++aa) {
            float2 p0 = sc[tid * 17 + aa * 2 + 0];
            float2 p1 = sc[tid * 17 + aa * 2 + 1];
            best = fmaxf(best, (p0.y + p1.y) / (p0.x + p1.x));
        }
        int lz2 = tid >> 4, ly2 = (tid >> 2) & 3, lx2 = tid & 3;
        int o = base_in + (g0z + lz2) * 1024 + (g0y + ly2) * 32 + (g0x + lx2);
        out[o] = best;
    }
}

extern "C" void kernel_launch(void* const* d_in, const int* in_sizes, int n_in,
                              void* d_out, int out_size, void* d_ws, size_t ws_size,
                              hipStream_t stream) {
    const float* values  = (const float*)d_in[0];
    const float* rewards = (const float*)d_in[1];
    const float* w_qk    = (const float*)d_in[2];
    const float* w_v     = (const float*)d_in[3];
    avi_kernel<<<NB * 512, 256, 0, stream>>>(values, rewards, w_qk, w_v,
                                             (float*)d_out);
}